// Round 3
// baseline (1723.811 us; speedup 1.0000x reference)
//
#include <hip/hip_runtime.h>
#include <hip/hip_bf16.h>

typedef unsigned short u16;
typedef __attribute__((ext_vector_type(8))) short bf16x8;
typedef __attribute__((ext_vector_type(8))) unsigned short u16x8;
typedef __attribute__((ext_vector_type(4))) float f32x4;

#define BB 16384
#define DD 2048
#define KEXT 2080   // 2048 x-cols + 16 ss cols + 16 zero pad
#define HH 1024
#define EE 16
#define TOPN 409

__device__ __forceinline__ u16 f2bf(float f) {
    union { float f; unsigned u; } c; c.f = f;
    unsigned r = c.u + 0x7fffu + ((c.u >> 16) & 1u);
    return (u16)(r >> 16);
}
__device__ __forceinline__ float bf2f(u16 h) {
    union { unsigned u; float f; } c; c.u = ((unsigned)h) << 16; return c.f;
}

__device__ __forceinline__ void ld16_lds(const void* g, void* l) {
    __builtin_amdgcn_global_load_lds(
        (const __attribute__((address_space(1))) unsigned int*)g,
        (__attribute__((address_space(3))) unsigned int*)l, 16, 0, 0);
}

// ---------------- prep: transpose/split big-GEMM weights to bf16 ----------------
__global__ __launch_bounds__(256)
void prep_w(const float* __restrict__ Ws1, const float* __restrict__ Wr1,
            u16* __restrict__ w1t, u16* __restrict__ wr1h, u16* __restrict__ wr1l)
{
    int idx = blockIdx.x * 256 + threadIdx.x;
    if (idx >= HH * KEXT) return;
    int n = idx / KEXT, k = idx % KEXT;
    float v1 = (k < DD) ? Ws1[(size_t)k * HH + n] : 0.0f;
    w1t[idx] = f2bf(v1);
    float v2 = (k < DD + EE) ? Wr1[(size_t)k * HH + n] : 0.0f;
    u16 h = f2bf(v2);
    wr1h[idx] = h;
    wr1l[idx] = f2bf(v2 - bf2f(h));
}

// ---------------- stats: 1 wave per row, register-resident ----------------
__global__ __launch_bounds__(256)
void stats_kernel(const float* __restrict__ x,
                  const float* __restrict__ Wk1, const float* __restrict__ bk1,
                  const float* __restrict__ Wk2, const float* __restrict__ bk2,
                  float* __restrict__ stats_out, u16* __restrict__ xh, u16* __restrict__ xl,
                  unsigned* __restrict__ kflags)
{
    const int wid = threadIdx.x >> 6;
    const int lane = threadIdx.x & 63;
    const int row = blockIdx.x * 4 + wid;
    const float* xr = x + (size_t)row * DD;

    float v[32];
    #pragma unroll
    for (int s = 0; s < 8; ++s) {
        float4 a = *(const float4*)(xr + s * 256 + lane * 4);
        v[s*4+0]=a.x; v[s*4+1]=a.y; v[s*4+2]=a.z; v[s*4+3]=a.w;
    }

    u16* ph = xh + (size_t)row * KEXT;
    u16* pl = xl + (size_t)row * KEXT;
    #pragma unroll
    for (int s = 0; s < 8; ++s) {
        union { u16 a[4]; unsigned long long q; } H, L;
        #pragma unroll
        for (int c = 0; c < 4; ++c) {
            float f = v[s*4+c];
            u16 h = f2bf(f);
            H.a[c] = h; L.a[c] = f2bf(f - bf2f(h));
        }
        *(unsigned long long*)(ph + s*256 + lane*4) = H.q;
        *(unsigned long long*)(pl + s*256 + lane*4) = L.q;
    }

    float s1 = 0;
    #pragma unroll
    for (int j = 0; j < 32; ++j) s1 += v[j];
    #pragma unroll
    for (int off = 32; off >= 1; off >>= 1) s1 += __shfl_xor(s1, off);
    const float mean = s1 * (1.0f/2048.0f);

    float s2=0, s3=0, sa=0, sq=0, zc=0, mx=0;
    #pragma unroll
    for (int j = 0; j < 32; ++j) {
        float d = v[j] - mean;
        s2 += d*d; s3 += d*d*d;
        float av = fabsf(v[j]);
        sa += av; sq += v[j]*v[j];
        mx = fmaxf(mx, av);
        zc += (v[j] == 0.0f) ? 1.0f : 0.0f;
    }
    #pragma unroll
    for (int off = 32; off >= 1; off >>= 1) {
        s2 += __shfl_xor(s2, off);
        s3 += __shfl_xor(s3, off);
        sa += __shfl_xor(sa, off);
        sq += __shfl_xor(sq, off);
        zc += __shfl_xor(zc, off);
        mx = fmaxf(mx, __shfl_xor(mx, off));
    }

    #pragma unroll
    for (int j = 0; j < 32; ++j) v[j] = fabsf(v[j]);

    unsigned lo = 0, hi = 0x7F800000u;
    while (lo < hi) {
        unsigned mid = (lo + hi) >> 1;
        float midf = __uint_as_float(mid);
        unsigned cnt = 0;
        #pragma unroll
        for (int j = 0; j < 32; ++j)
            cnt += (unsigned)__popcll(__ballot(v[j] > midf));
        if (cnt < TOPN) hi = mid; else lo = mid + 1;
    }
    const float T = __uint_as_float(lo);

    float cg = 0, sg = 0;
    #pragma unroll
    for (int j = 0; j < 32; ++j) {
        if (v[j] > T) { cg += 1.0f; sg += v[j]; }
    }
    #pragma unroll
    for (int off = 32; off >= 1; off >>= 1) { cg += __shfl_xor(cg, off); sg += __shfl_xor(sg, off); }

    if (lane == 0) {
        float top = sg + ((float)TOPN - cg) * T;
        float var_u = s2 * (1.0f/2047.0f);
        float stdv = sqrtf(var_u + 1e-8f);
        float st0 = zc * (1.0f/2048.0f);
        float st1 = var_u;
        float st2 = mx;
        float st3 = sqrtf(sq);
        float st4 = (s3 * (1.0f/2048.0f)) / (stdv*stdv*stdv);
        float st5 = top / (sa + 1e-8f);
        float* so = stats_out + (size_t)row * 6;
        so[0]=st0; so[1]=st1; so[2]=st2; so[3]=st3; so[4]=st4; so[5]=st5;
        float stv[6] = {st0,st1,st2,st3,st4,st5};
        float o = bk2[0];
        #pragma unroll
        for (int i = 0; i < 16; ++i) {
            float h = bk1[i];
            #pragma unroll
            for (int f = 0; f < 6; ++f) h += stv[f] * Wk1[f*16 + i];
            o += fmaxf(h, 0.0f) * Wk2[i];
        }
        float kr = 1.0f / (1.0f + expf(-o));
        float kv = 1.0f + 3.0f * kr;
        kflags[row] = (kv < 2.0f ? 1u : 0u) | (kv < 3.0f ? 0x10000u : 0u);
    }
}

// ---------------- k-median reduce ----------------
__global__ __launch_bounds__(1024)
void kmed_kernel(const unsigned* __restrict__ kflags, int* __restrict__ counters)
{
    const int t = threadIdx.x;
    unsigned s = 0;
    for (int i = t; i < BB; i += 1024) s += kflags[i];
    #pragma unroll
    for (int off = 32; off >= 1; off >>= 1) s += __shfl_xor(s, off);
    __shared__ unsigned red[16];
    if ((t & 63) == 0) red[t >> 6] = s;
    __syncthreads();
    if (t == 0) {
        unsigned tot = 0;
        #pragma unroll
        for (int w = 0; w < 16; ++w) tot += red[w];
        counters[0] = (int)(tot & 0xFFFFu);
        counters[1] = (int)(tot >> 16);
    }
}

// ---------------- big GEMM: O = relu(A@B^T + bias) fp32 out; fused 3-term if SPLIT3 ----------------
template<bool SPLIT3>
__global__ __launch_bounds__(256)
void gemm_tile(const u16* __restrict__ Ah, const u16* __restrict__ Al,
               const u16* __restrict__ Bh, const u16* __restrict__ Bl,
               const float* __restrict__ bias, float* __restrict__ O,
               int kiters, int astride, int bstride)
{
    __shared__ u16 AsH[128*32];
    __shared__ u16 BsH[128*32];
    __shared__ u16 AsL[128*32];
    __shared__ u16 BsL[128*32];
    const int t = threadIdx.x;
    const int m0 = blockIdx.y * 128;
    const int n0 = blockIdx.x * 128;
    const int wid = t >> 6, lane = t & 63, l16 = lane & 15, q = lane >> 4;
    const int wm = (wid & 1) * 64, wn = (wid >> 1) * 64;

    f32x4 acc[4][4] = {};

    for (int it = 0; it < kiters; ++it) {
        const int k0 = it * 32;
        __syncthreads();
        #pragma unroll
        for (int s = 0; s < 2; ++s) {
            int seg = t + s * 256;
            int row = seg >> 2;
            int kq = (seg & 3) * 8;
            size_t aoff = (size_t)(m0 + row) * astride + k0 + kq;
            size_t boff = (size_t)(n0 + row) * bstride + k0 + kq;
            ld16_lds(Ah + aoff, (void*)(AsH + seg * 8));
            ld16_lds(Bh + boff, (void*)(BsH + seg * 8));
            if constexpr (SPLIT3) {
                ld16_lds(Al + aoff, (void*)(AsL + seg * 8));
                ld16_lds(Bl + boff, (void*)(BsL + seg * 8));
            }
        }
        __syncthreads();
        bf16x8 afh[4], bfh[4], afl[4], bfl[4];
        #pragma unroll
        for (int i = 0; i < 4; ++i) {
            afh[i] = *(const bf16x8*)(AsH + (wm + 16*i + l16) * 32 + q * 8);
            bfh[i] = *(const bf16x8*)(BsH + (wn + 16*i + l16) * 32 + q * 8);
            if constexpr (SPLIT3) {
                afl[i] = *(const bf16x8*)(AsL + (wm + 16*i + l16) * 32 + q * 8);
                bfl[i] = *(const bf16x8*)(BsL + (wn + 16*i + l16) * 32 + q * 8);
            }
        }
        #pragma unroll
        for (int i = 0; i < 4; ++i)
            #pragma unroll
            for (int j = 0; j < 4; ++j) {
                acc[i][j] = __builtin_amdgcn_mfma_f32_16x16x32_bf16(afh[i], bfh[j], acc[i][j], 0, 0, 0);
                if constexpr (SPLIT3) {
                    acc[i][j] = __builtin_amdgcn_mfma_f32_16x16x32_bf16(afh[i], bfl[j], acc[i][j], 0, 0, 0);
                    acc[i][j] = __builtin_amdgcn_mfma_f32_16x16x32_bf16(afl[i], bfh[j], acc[i][j], 0, 0, 0);
                }
            }
    }
    #pragma unroll
    for (int j = 0; j < 4; ++j) {
        int col = n0 + wn + 16*j + l16;
        float bv = bias[col];
        #pragma unroll
        for (int i = 0; i < 4; ++i)
            #pragma unroll
            for (int r = 0; r < 4; ++r) {
                int row = m0 + wm + 16*i + q*4 + r;
                float vv = acc[i][j][r] + bv;
                O[(size_t)row * HH + col] = vv > 0.0f ? vv : 0.0f;
            }
    }
}

// ---------------- sims = x @ pat^T, fp32-exact, LDS-staged pattern (2 halves) ----------------
__global__ __launch_bounds__(1024)
void sims_kernel(const float* __restrict__ x, const float* __restrict__ pat,
                 float* __restrict__ sims)
{
    __shared__ float ps[8 * DD];   // 64 KB: 8 experts per half
    const int t = threadIdx.x;
    const int wv = t >> 6, ln = t & 63;
    const int rbase = blockIdx.x * 64 + wv * 4;
    for (int half = 0; half < 2; ++half) {
        __syncthreads();
        const float4* src = (const float4*)(pat + (size_t)half * 8 * DD);
        #pragma unroll
        for (int i = 0; i < 4; ++i) ((float4*)ps)[i * 1024 + t] = src[i * 1024 + t];
        __syncthreads();
        for (int r = 0; r < 4; ++r) {
            const int row = rbase + r;
            const float* xr = x + (size_t)row * DD;
            float4 xv[8];
            #pragma unroll
            for (int c = 0; c < 8; ++c) xv[c] = *(const float4*)(xr + c * 256 + ln * 4);
            float acc[8] = {0,0,0,0,0,0,0,0};
            #pragma unroll
            for (int c = 0; c < 8; ++c) {
                int colb = c * 256 + ln * 4;
                #pragma unroll
                for (int e = 0; e < 8; ++e) {
                    float4 pv = *(const float4*)(ps + e * DD + colb);
                    acc[e] += xv[c].x*pv.x + xv[c].y*pv.y + xv[c].z*pv.z + xv[c].w*pv.w;
                }
            }
            #pragma unroll
            for (int e = 0; e < 8; ++e)
                #pragma unroll
                for (int off = 32; off >= 1; off >>= 1)
                    acc[e] += __shfl_xor(acc[e], off);
            if (ln == 0) {
                float4 o0 = {acc[0],acc[1],acc[2],acc[3]};
                float4 o1 = {acc[4],acc[5],acc[6],acc[7]};
                float4* dst = (float4*)(sims + (size_t)row * EE + half * 8);
                dst[0] = o0; dst[1] = o1;
            }
        }
    }
}

// ---------------- spec = h1@Ws2; ss = sigmoid(sims+spec+bs2) -> split-bf16 cols of xh/xl ----------------
__global__ __launch_bounds__(1024)
void specss_kernel(const float* __restrict__ h1, const float* __restrict__ Ws2,
                   const float* __restrict__ bs2, const float* __restrict__ sims,
                   u16* __restrict__ xh, u16* __restrict__ xl)
{
    __shared__ float ws[HH * EE];   // 64 KB, [n][e] row-major (= Ws2 layout)
    const int t = threadIdx.x;
    const int wv = t >> 6, ln = t & 63;
    #pragma unroll
    for (int i = 0; i < 4; ++i) ((float4*)ws)[i * 1024 + t] = ((const float4*)Ws2)[i * 1024 + t];
    __syncthreads();
    const int rbase = blockIdx.x * 64 + wv * 4;
    for (int r = 0; r < 4; ++r) {
        const int row = rbase + r;
        const float* hr = h1 + (size_t)row * HH;
        float acc[16];
        #pragma unroll
        for (int e = 0; e < 16; ++e) acc[e] = 0.0f;
        #pragma unroll
        for (int c = 0; c < 4; ++c) {
            float4 hv = *(const float4*)(hr + c * 256 + ln * 4);
            float hva[4] = {hv.x, hv.y, hv.z, hv.w};
            int nb = c * 256 + ln * 4;
            #pragma unroll
            for (int jn = 0; jn < 4; ++jn) {
                const float4* wr = (const float4*)(ws + (size_t)(nb + jn) * EE);
                float4 w0 = wr[0], w1 = wr[1], w2 = wr[2], w3 = wr[3];
                float hj = hva[jn];
                acc[0]+=hj*w0.x; acc[1]+=hj*w0.y; acc[2]+=hj*w0.z; acc[3]+=hj*w0.w;
                acc[4]+=hj*w1.x; acc[5]+=hj*w1.y; acc[6]+=hj*w1.z; acc[7]+=hj*w1.w;
                acc[8]+=hj*w2.x; acc[9]+=hj*w2.y; acc[10]+=hj*w2.z; acc[11]+=hj*w2.w;
                acc[12]+=hj*w3.x; acc[13]+=hj*w3.y; acc[14]+=hj*w3.z; acc[15]+=hj*w3.w;
            }
        }
        #pragma unroll
        for (int e = 0; e < 16; ++e)
            #pragma unroll
            for (int off = 32; off >= 1; off >>= 1)
                acc[e] += __shfl_xor(acc[e], off);
        if (ln == 0) {
            union { u16 a[8]; u16x8 vec; } H0, H1, L0, L1;
            #pragma unroll
            for (int e = 0; e < 16; ++e) {
                float sarg = acc[e] + sims[(size_t)row*EE + e] + bs2[e];
                float ssv = 1.0f / (1.0f + expf(-sarg));
                u16 h = f2bf(ssv);
                u16 lo = f2bf(ssv - bf2f(h));
                if (e < 8) { H0.a[e] = h; L0.a[e] = lo; } else { H1.a[e-8] = h; L1.a[e-8] = lo; }
            }
            u16x8 z = {0,0,0,0,0,0,0,0};
            u16* ph = xh + (size_t)row * KEXT + DD;
            u16* pl = xl + (size_t)row * KEXT + DD;
            *(u16x8*)(ph)      = H0.vec;
            *(u16x8*)(ph + 8)  = H1.vec;
            *(u16x8*)(ph + 16) = z;
            *(u16x8*)(ph + 24) = z;
            *(u16x8*)(pl)      = L0.vec;
            *(u16x8*)(pl + 8)  = L1.vec;
            *(u16x8*)(pl + 16) = z;
            *(u16x8*)(pl + 24) = z;
        }
    }
}

// ---------------- logits = h2@Wr2 + br2; softmax; top4; gates (fp32-exact) ----------------
__global__ __launch_bounds__(1024)
void logits_final(const float* __restrict__ h2, const float* __restrict__ Wr2,
                  const float* __restrict__ br2, const int* __restrict__ counters,
                  float* __restrict__ out_gates, float* __restrict__ out_idx,
                  float* __restrict__ out_probs)
{
    __shared__ float ws[HH * EE];   // 64 KB
    const int t = threadIdx.x;
    const int wv = t >> 6, ln = t & 63;
    #pragma unroll
    for (int i = 0; i < 4; ++i) ((float4*)ws)[i * 1024 + t] = ((const float4*)Wr2)[i * 1024 + t];
    __syncthreads();
    const int rbase = blockIdx.x * 64 + wv * 4;
    for (int r = 0; r < 4; ++r) {
        const int row = rbase + r;
        const float* hr = h2 + (size_t)row * HH;
        float acc[16];
        #pragma unroll
        for (int e = 0; e < 16; ++e) acc[e] = 0.0f;
        #pragma unroll
        for (int c = 0; c < 4; ++c) {
            float4 hv = *(const float4*)(hr + c * 256 + ln * 4);
            float hva[4] = {hv.x, hv.y, hv.z, hv.w};
            int nb = c * 256 + ln * 4;
            #pragma unroll
            for (int jn = 0; jn < 4; ++jn) {
                const float4* wr = (const float4*)(ws + (size_t)(nb + jn) * EE);
                float4 w0 = wr[0], w1 = wr[1], w2 = wr[2], w3 = wr[3];
                float hj = hva[jn];
                acc[0]+=hj*w0.x; acc[1]+=hj*w0.y; acc[2]+=hj*w0.z; acc[3]+=hj*w0.w;
                acc[4]+=hj*w1.x; acc[5]+=hj*w1.y; acc[6]+=hj*w1.z; acc[7]+=hj*w1.w;
                acc[8]+=hj*w2.x; acc[9]+=hj*w2.y; acc[10]+=hj*w2.z; acc[11]+=hj*w2.w;
                acc[12]+=hj*w3.x; acc[13]+=hj*w3.y; acc[14]+=hj*w3.z; acc[15]+=hj*w3.w;
            }
        }
        #pragma unroll
        for (int e = 0; e < 16; ++e)
            #pragma unroll
            for (int off = 32; off >= 1; off >>= 1)
                acc[e] += __shfl_xor(acc[e], off);
        if (ln == 0) {
            float lg[16];
            float m = -1e30f;
            #pragma unroll
            for (int e = 0; e < 16; ++e) {
                lg[e] = acc[e] + br2[e];
                m = fmaxf(m, lg[e]);
            }
            float p[16], den = 0.0f;
            #pragma unroll
            for (int e = 0; e < 16; ++e) { p[e] = expf(lg[e] - m); den += p[e]; }
            float inv = 1.0f / den;
            #pragma unroll
            for (int e = 0; e < 16; ++e) p[e] *= inv;
            float4* pd = (float4*)(out_probs + (size_t)row * EE);
            pd[0] = {p[0],p[1],p[2],p[3]};
            pd[1] = {p[4],p[5],p[6],p[7]};
            pd[2] = {p[8],p[9],p[10],p[11]};
            pd[3] = {p[12],p[13],p[14],p[15]};
            float tv[4]; int ti[4];
            unsigned used = 0;
            #pragma unroll
            for (int s = 0; s < 4; ++s) {
                float best = -1e30f; int bi = 0;
                #pragma unroll
                for (int e = 0; e < 16; ++e) {
                    if (!((used >> e) & 1u) && p[e] > best) { best = p[e]; bi = e; }
                }
                used |= 1u << bi;
                tv[s] = best; ti[s] = bi;
            }
            int c2 = counters[0], c3 = counters[1];
            int k = (c2 >= 8192) ? 1 : ((c3 >= 8192) ? 2 : 3);
            float g[4] = {0,0,0,0};
            float d2 = 0.0f;
            for (int s = 0; s < k; ++s) { g[s] = expf(tv[s] - tv[0]); d2 += g[s]; }
            float i2 = 1.0f / d2;
            float4 gv = { (0 < k) ? g[0]*i2 : 0.0f, (1 < k) ? g[1]*i2 : 0.0f,
                          (2 < k) ? g[2]*i2 : 0.0f, (3 < k) ? g[3]*i2 : 0.0f };
            *(float4*)(out_gates + (size_t)row * 4) = gv;
            float4 iv = { (float)ti[0], (float)ti[1], (float)ti[2], (float)ti[3] };
            *(float4*)(out_idx + (size_t)row * 4) = iv;
        }
    }
}

// ---------------- host launch ----------------
extern "C" void kernel_launch(void* const* d_in, const int* in_sizes, int n_in,
                              void* d_out, int out_size, void* d_ws, size_t ws_size,
                              hipStream_t stream) {
    const float* x   = (const float*)d_in[0];
    const float* pat = (const float*)d_in[1];
    const float* Ws1 = (const float*)d_in[2];
    const float* bs1 = (const float*)d_in[3];
    const float* Ws2 = (const float*)d_in[4];
    const float* bs2 = (const float*)d_in[5];
    const float* Wr1 = (const float*)d_in[6];
    const float* br1 = (const float*)d_in[7];
    const float* Wr2 = (const float*)d_in[8];
    const float* br2 = (const float*)d_in[9];
    const float* Wk1 = (const float*)d_in[10];
    const float* bk1 = (const float*)d_in[11];
    const float* Wk2 = (const float*)d_in[12];
    const float* bk2 = (const float*)d_in[13];

    char* ws = (char*)d_ws;
    size_t off = 0;
    auto alloc = [&](size_t bytes) { char* p = ws + off; off += (bytes + 255) & ~(size_t)255; return p; };
    u16* xh     = (u16*)alloc((size_t)BB * KEXT * 2);
    u16* xl     = (u16*)alloc((size_t)BB * KEXT * 2);
    u16* w1t    = (u16*)alloc((size_t)HH * KEXT * 2);
    u16* wr1h   = (u16*)alloc((size_t)HH * KEXT * 2);
    u16* wr1l   = (u16*)alloc((size_t)HH * KEXT * 2);
    float* h1     = (float*)alloc((size_t)BB * HH * 4);   // h2 aliases h1 (h1 dead before gemm2)
    float* sims   = (float*)alloc((size_t)BB * EE * 4);
    unsigned* kflags = (unsigned*)alloc((size_t)BB * 4);
    int* cnt      = (int*)alloc(64);
    float* h2 = h1;

    float* out        = (float*)d_out;
    float* out_gates  = out;
    float* out_idx    = out + (size_t)BB * 4;
    float* out_probs  = out + (size_t)BB * 8;
    float* out_stats  = out + (size_t)BB * 24;

    prep_w<<<(HH*KEXT + 255)/256, 256, 0, stream>>>(Ws1, Wr1, w1t, wr1h, wr1l);

    stats_kernel<<<BB/4, 256, 0, stream>>>(x, Wk1, bk1, Wk2, bk2, out_stats, xh, xl, kflags);

    kmed_kernel<<<1, 1024, 0, stream>>>(kflags, cnt);

    // sims = x @ pat^T (fp32-exact)
    sims_kernel<<<BB/64, 1024, 0, stream>>>(x, pat, sims);

    // h1 = relu(x@Ws1 + bs1), plain bf16 inputs, fp32 out
    gemm_tile<false><<<dim3(8, 128), 256, 0, stream>>>(
        xh, nullptr, w1t, nullptr, bs1, h1, 64, KEXT, KEXT);

    // spec + ss (fp32-exact spec from fp32 h1)
    specss_kernel<<<BB/64, 1024, 0, stream>>>(h1, Ws2, bs2, sims, xh, xl);

    // h2 = relu(ri@Wr1 + br1), fused 3-term split, fp32 out
    gemm_tile<true><<<dim3(8, 128), 256, 0, stream>>>(
        xh, xl, wr1h, wr1l, br1, h2, 65, KEXT, KEXT);

    // logits + softmax + top4 + gates (fp32-exact given h2)
    logits_final<<<BB/64, 1024, 0, stream>>>(h2, Wr2, br2, cnt, out_gates, out_idx, out_probs);
}

// Round 4
// 733.952 us; speedup vs baseline: 2.3487x; 2.3487x over previous
//
#include <hip/hip_runtime.h>
#include <hip/hip_bf16.h>

typedef unsigned short u16;
typedef __attribute__((ext_vector_type(8))) short bf16x8;
typedef __attribute__((ext_vector_type(8))) unsigned short u16x8;
typedef __attribute__((ext_vector_type(4))) float f32x4;

#define BB 16384
#define DD 2048
#define KEXT 2080   // 2048 x-cols + 16 ss cols + 16 zero pad
#define HH 1024
#define EE 16
#define TOPN 409

__device__ __forceinline__ u16 f2bf(float f) {
    union { float f; unsigned u; } c; c.f = f;
    unsigned r = c.u + 0x7fffu + ((c.u >> 16) & 1u);
    return (u16)(r >> 16);
}
__device__ __forceinline__ float bf2f(u16 h) {
    union { unsigned u; float f; } c; c.u = ((unsigned)h) << 16; return c.f;
}

__device__ __forceinline__ void ld16_lds(const void* g, void* l) {
    __builtin_amdgcn_global_load_lds(
        (const __attribute__((address_space(1))) unsigned int*)g,
        (__attribute__((address_space(3))) unsigned int*)l, 16, 0, 0);
}

// ---------------- prep: transpose/split weights to bf16 ----------------
__global__ __launch_bounds__(256)
void prep_w(const float* __restrict__ Ws1, const float* __restrict__ Wr1,
            const float* __restrict__ Ws2, const float* __restrict__ Wr2,
            const float* __restrict__ pat,
            u16* __restrict__ w1t, u16* __restrict__ wr1h, u16* __restrict__ wr1l,
            u16* __restrict__ w2t1, u16* __restrict__ wr2th, u16* __restrict__ wr2tl,
            u16* __restrict__ patTh, u16* __restrict__ patTl)
{
    int idx = blockIdx.x * 256 + threadIdx.x;
    if (idx < HH * KEXT) {
        int n = idx / KEXT, k = idx % KEXT;
        float v1 = (k < DD) ? Ws1[(size_t)k * HH + n] : 0.0f;
        w1t[idx] = f2bf(v1);
        float v2 = (k < DD + EE) ? Wr1[(size_t)k * HH + n] : 0.0f;
        u16 h = f2bf(v2);
        wr1h[idx] = h;
        wr1l[idx] = f2bf(v2 - bf2f(h));
    }
    if (idx < EE * HH) {
        int e = idx / HH, n = idx % HH;
        w2t1[idx] = f2bf(Ws2[(size_t)n * EE + e]);
        float v = Wr2[(size_t)n * EE + e];
        u16 h = f2bf(v);
        wr2th[idx] = h;
        wr2tl[idx] = f2bf(v - bf2f(h));
    }
    if (idx < EE * DD) {
        float v = pat[idx];   // pat is [E][D] row-major = transposed layout already
        u16 h = f2bf(v);
        patTh[idx] = h;
        patTl[idx] = f2bf(v - bf2f(h));
    }
}

// ---------------- stats: 1 wave per row, register-resident ----------------
__global__ __launch_bounds__(256)
void stats_kernel(const float* __restrict__ x,
                  const float* __restrict__ Wk1, const float* __restrict__ bk1,
                  const float* __restrict__ Wk2, const float* __restrict__ bk2,
                  float* __restrict__ stats_out, u16* __restrict__ xh, u16* __restrict__ xl,
                  unsigned* __restrict__ kflags)
{
    const int wid = threadIdx.x >> 6;
    const int lane = threadIdx.x & 63;
    const int row = blockIdx.x * 4 + wid;
    const float* xr = x + (size_t)row * DD;

    float v[32];
    #pragma unroll
    for (int s = 0; s < 8; ++s) {
        float4 a = *(const float4*)(xr + s * 256 + lane * 4);
        v[s*4+0]=a.x; v[s*4+1]=a.y; v[s*4+2]=a.z; v[s*4+3]=a.w;
    }

    u16* ph = xh + (size_t)row * KEXT;
    u16* pl = xl + (size_t)row * KEXT;
    #pragma unroll
    for (int s = 0; s < 8; ++s) {
        union { u16 a[4]; unsigned long long q; } H, L;
        #pragma unroll
        for (int c = 0; c < 4; ++c) {
            float f = v[s*4+c];
            u16 h = f2bf(f);
            H.a[c] = h; L.a[c] = f2bf(f - bf2f(h));
        }
        *(unsigned long long*)(ph + s*256 + lane*4) = H.q;
        *(unsigned long long*)(pl + s*256 + lane*4) = L.q;
    }

    float s1 = 0;
    #pragma unroll
    for (int j = 0; j < 32; ++j) s1 += v[j];
    #pragma unroll
    for (int off = 32; off >= 1; off >>= 1) s1 += __shfl_xor(s1, off);
    const float mean = s1 * (1.0f/2048.0f);

    float s2=0, s3=0, sa=0, sq=0, zc=0, mx=0;
    #pragma unroll
    for (int j = 0; j < 32; ++j) {
        float d = v[j] - mean;
        s2 += d*d; s3 += d*d*d;
        float av = fabsf(v[j]);
        sa += av; sq += v[j]*v[j];
        mx = fmaxf(mx, av);
        zc += (v[j] == 0.0f) ? 1.0f : 0.0f;
    }
    #pragma unroll
    for (int off = 32; off >= 1; off >>= 1) {
        s2 += __shfl_xor(s2, off);
        s3 += __shfl_xor(s3, off);
        sa += __shfl_xor(sa, off);
        sq += __shfl_xor(sq, off);
        zc += __shfl_xor(zc, off);
        mx = fmaxf(mx, __shfl_xor(mx, off));
    }

    #pragma unroll
    for (int j = 0; j < 32; ++j) v[j] = fabsf(v[j]);

    unsigned lo = 0, hi = 0x7F800000u;
    while (lo < hi) {
        unsigned mid = (lo + hi) >> 1;
        float midf = __uint_as_float(mid);
        unsigned cnt = 0;
        #pragma unroll
        for (int j = 0; j < 32; ++j)
            cnt += (unsigned)__popcll(__ballot(v[j] > midf));
        if (cnt < TOPN) hi = mid; else lo = mid + 1;
    }
    const float T = __uint_as_float(lo);

    float cg = 0, sg = 0;
    #pragma unroll
    for (int j = 0; j < 32; ++j) {
        if (v[j] > T) { cg += 1.0f; sg += v[j]; }
    }
    #pragma unroll
    for (int off = 32; off >= 1; off >>= 1) { cg += __shfl_xor(cg, off); sg += __shfl_xor(sg, off); }

    if (lane == 0) {
        float top = sg + ((float)TOPN - cg) * T;
        float var_u = s2 * (1.0f/2047.0f);
        float stdv = sqrtf(var_u + 1e-8f);
        float st0 = zc * (1.0f/2048.0f);
        float st1 = var_u;
        float st2 = mx;
        float st3 = sqrtf(sq);
        float st4 = (s3 * (1.0f/2048.0f)) / (stdv*stdv*stdv);
        float st5 = top / (sa + 1e-8f);
        float* so = stats_out + (size_t)row * 6;
        so[0]=st0; so[1]=st1; so[2]=st2; so[3]=st3; so[4]=st4; so[5]=st5;
        float stv[6] = {st0,st1,st2,st3,st4,st5};
        float o = bk2[0];
        #pragma unroll
        for (int i = 0; i < 16; ++i) {
            float h = bk1[i];
            #pragma unroll
            for (int f = 0; f < 6; ++f) h += stv[f] * Wk1[f*16 + i];
            o += fmaxf(h, 0.0f) * Wk2[i];
        }
        float kr = 1.0f / (1.0f + expf(-o));
        float kv = 1.0f + 3.0f * kr;
        kflags[row] = (kv < 2.0f ? 1u : 0u) | (kv < 3.0f ? 0x10000u : 0u);
    }
}

// ---------------- k-median reduce ----------------
__global__ __launch_bounds__(1024)
void kmed_kernel(const unsigned* __restrict__ kflags, int* __restrict__ counters)
{
    const int t = threadIdx.x;
    unsigned s = 0;
    for (int i = t; i < BB; i += 1024) s += kflags[i];
    #pragma unroll
    for (int off = 32; off >= 1; off >>= 1) s += __shfl_xor(s, off);
    __shared__ unsigned red[16];
    if ((t & 63) == 0) red[t >> 6] = s;
    __syncthreads();
    if (t == 0) {
        unsigned tot = 0;
        #pragma unroll
        for (int w = 0; w < 16; ++w) tot += red[w];
        counters[0] = (int)(tot & 0xFFFFu);
        counters[1] = (int)(tot >> 16);
    }
}

// ---------------- big GEMM: O = relu(A@B^T + bias) -> bf16 (split pair if OSPLIT) ----------------
template<bool SPLIT3, bool OSPLIT>
__global__ __launch_bounds__(256)
void gemm_tile(const u16* __restrict__ Ah, const u16* __restrict__ Al,
               const u16* __restrict__ Bh, const u16* __restrict__ Bl,
               const float* __restrict__ bias,
               u16* __restrict__ Oh, u16* __restrict__ Ol,
               int kiters, int astride, int bstride)
{
    __shared__ u16 AsH[128*32];
    __shared__ u16 BsH[128*32];
    __shared__ u16 AsL[SPLIT3 ? 128*32 : 8];
    __shared__ u16 BsL[SPLIT3 ? 128*32 : 8];
    const int t = threadIdx.x;
    const int m0 = blockIdx.y * 128;
    const int n0 = blockIdx.x * 128;
    const int wid = t >> 6, lane = t & 63, l16 = lane & 15, q = lane >> 4;
    const int wm = (wid & 1) * 64, wn = (wid >> 1) * 64;

    f32x4 acc[4][4] = {};

    for (int it = 0; it < kiters; ++it) {
        const int k0 = it * 32;
        __syncthreads();
        #pragma unroll
        for (int s = 0; s < 2; ++s) {
            int seg = t + s * 256;
            int row = seg >> 2;
            int kq = (seg & 3) * 8;
            size_t aoff = (size_t)(m0 + row) * astride + k0 + kq;
            size_t boff = (size_t)(n0 + row) * bstride + k0 + kq;
            ld16_lds(Ah + aoff, (void*)(AsH + seg * 8));
            ld16_lds(Bh + boff, (void*)(BsH + seg * 8));
            if constexpr (SPLIT3) {
                ld16_lds(Al + aoff, (void*)(AsL + seg * 8));
                ld16_lds(Bl + boff, (void*)(BsL + seg * 8));
            }
        }
        __syncthreads();
        bf16x8 afh[4], bfh[4], afl[4], bfl[4];
        #pragma unroll
        for (int i = 0; i < 4; ++i) {
            afh[i] = *(const bf16x8*)(AsH + (wm + 16*i + l16) * 32 + q * 8);
            bfh[i] = *(const bf16x8*)(BsH + (wn + 16*i + l16) * 32 + q * 8);
            if constexpr (SPLIT3) {
                afl[i] = *(const bf16x8*)(AsL + (wm + 16*i + l16) * 32 + q * 8);
                bfl[i] = *(const bf16x8*)(BsL + (wn + 16*i + l16) * 32 + q * 8);
            }
        }
        #pragma unroll
        for (int i = 0; i < 4; ++i)
            #pragma unroll
            for (int j = 0; j < 4; ++j) {
                acc[i][j] = __builtin_amdgcn_mfma_f32_16x16x32_bf16(afh[i], bfh[j], acc[i][j], 0, 0, 0);
                if constexpr (SPLIT3) {
                    acc[i][j] = __builtin_amdgcn_mfma_f32_16x16x32_bf16(afh[i], bfl[j], acc[i][j], 0, 0, 0);
                    acc[i][j] = __builtin_amdgcn_mfma_f32_16x16x32_bf16(afl[i], bfh[j], acc[i][j], 0, 0, 0);
                }
            }
    }
    #pragma unroll
    for (int j = 0; j < 4; ++j) {
        int col = n0 + wn + 16*j + l16;
        float bv = bias[col];
        #pragma unroll
        for (int i = 0; i < 4; ++i)
            #pragma unroll
            for (int r = 0; r < 4; ++r) {
                int row = m0 + wm + 16*i + q*4 + r;
                float vv = acc[i][j][r] + bv;
                vv = vv > 0.0f ? vv : 0.0f;
                u16 h = f2bf(vv);
                Oh[(size_t)row * HH + col] = h;
                if constexpr (OSPLIT) Ol[(size_t)row * HH + col] = f2bf(vv - bf2f(h));
            }
    }
}

// ---------------- thinA: simspec = x@pat^T (3-term) + h1@Ws2; ss epilogue -> xh/xl cols ----------------
__global__ __launch_bounds__(256)
void thinA(const u16* __restrict__ xh, const u16* __restrict__ xl,
           const u16* __restrict__ patTh, const u16* __restrict__ patTl,
           const u16* __restrict__ ha, const u16* __restrict__ w2t,
           const float* __restrict__ bs2,
           u16* __restrict__ xh_w, u16* __restrict__ xl_w)
{
    const int t = threadIdx.x;
    const int wid = t >> 6, lane = t & 63, l16 = lane & 15, q = lane >> 4;
    const int m0 = blockIdx.x * 16;
    f32x4 acc = {};
    // sims: 3-term split over K=2048 (xh*path + xh*patl + xl*path)
    for (int it = wid; it < 64; it += 4) {
        const int k0 = it * 32;
        bf16x8 a0 = *(const bf16x8*)(xh + (size_t)(m0 + l16) * KEXT + k0 + q*8);
        bf16x8 a1 = *(const bf16x8*)(xl + (size_t)(m0 + l16) * KEXT + k0 + q*8);
        bf16x8 b0 = *(const bf16x8*)(patTh + (size_t)l16 * DD + k0 + q*8);
        bf16x8 b1 = *(const bf16x8*)(patTl + (size_t)l16 * DD + k0 + q*8);
        acc = __builtin_amdgcn_mfma_f32_16x16x32_bf16(a0, b0, acc, 0, 0, 0);
        acc = __builtin_amdgcn_mfma_f32_16x16x32_bf16(a0, b1, acc, 0, 0, 0);
        acc = __builtin_amdgcn_mfma_f32_16x16x32_bf16(a1, b0, acc, 0, 0, 0);
    }
    // spec: h1 @ Ws2^T over K=1024
    for (int it = wid; it < 32; it += 4) {
        const int k0 = it * 32;
        bf16x8 a = *(const bf16x8*)(ha + (size_t)(m0 + l16) * HH + k0 + q*8);
        bf16x8 b = *(const bf16x8*)(w2t + (size_t)l16 * HH + k0 + q*8);
        acc = __builtin_amdgcn_mfma_f32_16x16x32_bf16(a, b, acc, 0, 0, 0);
    }
    __shared__ f32x4 red[4][64];
    red[wid][lane] = acc;
    __syncthreads();
    if (wid == 0) {
        f32x4 v = red[0][lane];
        #pragma unroll
        for (int w = 1; w < 4; ++w) {
            f32x4 o = red[w][lane];
            v[0]+=o[0]; v[1]+=o[1]; v[2]+=o[2]; v[3]+=o[3];
        }
        const float b2 = bs2[l16];
        #pragma unroll
        for (int r = 0; r < 4; ++r) {
            int row = m0 + q*4 + r;
            float ssv = 1.0f / (1.0f + expf(-(v[r] + b2)));
            u16 h = f2bf(ssv);
            u16 lo = f2bf(ssv - bf2f(h));
            xh_w[(size_t)row * KEXT + DD + l16] = h;
            xl_w[(size_t)row * KEXT + DD + l16] = lo;
            xh_w[(size_t)row * KEXT + DD + 16 + l16] = 0;
            xl_w[(size_t)row * KEXT + DD + 16 + l16] = 0;
        }
    }
}

// ---------------- thinB: logits = h2@Wr2 (3-term) + br2; softmax+top4+gates epilogue ----------------
__global__ __launch_bounds__(256)
void thinB(const u16* __restrict__ hh, const u16* __restrict__ hl,
           const u16* __restrict__ wr2th, const u16* __restrict__ wr2tl,
           const float* __restrict__ br2, const int* __restrict__ counters,
           float* __restrict__ out_gates, float* __restrict__ out_idx,
           float* __restrict__ out_probs)
{
    const int t = threadIdx.x;
    const int wid = t >> 6, lane = t & 63, l16 = lane & 15, q = lane >> 4;
    const int m0 = blockIdx.x * 16;
    f32x4 acc = {};
    for (int it = wid; it < 32; it += 4) {
        const int k0 = it * 32;
        bf16x8 a0 = *(const bf16x8*)(hh + (size_t)(m0 + l16) * HH + k0 + q*8);
        bf16x8 a1 = *(const bf16x8*)(hl + (size_t)(m0 + l16) * HH + k0 + q*8);
        bf16x8 b0 = *(const bf16x8*)(wr2th + (size_t)l16 * HH + k0 + q*8);
        bf16x8 b1 = *(const bf16x8*)(wr2tl + (size_t)l16 * HH + k0 + q*8);
        acc = __builtin_amdgcn_mfma_f32_16x16x32_bf16(a0, b0, acc, 0, 0, 0);
        acc = __builtin_amdgcn_mfma_f32_16x16x32_bf16(a0, b1, acc, 0, 0, 0);
        acc = __builtin_amdgcn_mfma_f32_16x16x32_bf16(a1, b0, acc, 0, 0, 0);
    }
    __shared__ f32x4 red[4][64];
    red[wid][lane] = acc;
    __syncthreads();
    if (wid != 0) return;
    f32x4 v = red[0][lane];
    #pragma unroll
    for (int w = 1; w < 4; ++w) {
        f32x4 o = red[w][lane];
        v[0]+=o[0]; v[1]+=o[1]; v[2]+=o[2]; v[3]+=o[3];
    }
    const float b2 = br2[l16];
    const int c2 = counters[0], c3 = counters[1];
    const int k = (c2 >= 8192) ? 1 : ((c3 >= 8192) ? 2 : 3);
    #pragma unroll
    for (int r = 0; r < 4; ++r) {
        const int row = m0 + q*4 + r;
        float lg = v[r] + b2;
        // softmax across the 16 lanes of this quarter-wave group
        float mxv = lg;
        #pragma unroll
        for (int off = 1; off < 16; off <<= 1) mxv = fmaxf(mxv, __shfl_xor(mxv, off));
        float e = expf(lg - mxv);
        float den = e;
        #pragma unroll
        for (int off = 1; off < 16; off <<= 1) den += __shfl_xor(den, off);
        float p = e / den;
        out_probs[(size_t)row * EE + l16] = p;
        // top-4 by keyed max (tie -> lower index, matching lax.top_k)
        int kcur = (int)((__float_as_uint(p) & ~15u) | (15u - (unsigned)l16));
        float tv[4]; int ti[4];
        #pragma unroll
        for (int s = 0; s < 4; ++s) {
            int kk = kcur;
            #pragma unroll
            for (int off = 1; off < 16; off <<= 1) kk = max(kk, __shfl_xor(kk, off));
            int widx = 15 - (kk & 15);
            ti[s] = widx;
            tv[s] = __shfl(p, q * 16 + widx);
            if (l16 == widx) kcur = 0;
        }
        float den2 = 0.0f;
        float g[4];
        #pragma unroll
        for (int s = 0; s < 4; ++s) {
            g[s] = expf(tv[s] - tv[0]);
            if (s < k) den2 += g[s];
        }
        if (l16 < 4) {
            out_gates[(size_t)row * 4 + l16] = (l16 < k) ? g[l16] / den2 : 0.0f;
            out_idx[(size_t)row * 4 + l16] = (float)ti[l16];
        }
    }
}

// ---------------- host launch ----------------
extern "C" void kernel_launch(void* const* d_in, const int* in_sizes, int n_in,
                              void* d_out, int out_size, void* d_ws, size_t ws_size,
                              hipStream_t stream) {
    const float* x   = (const float*)d_in[0];
    const float* pat = (const float*)d_in[1];
    const float* Ws1 = (const float*)d_in[2];
    const float* bs1 = (const float*)d_in[3];
    const float* Ws2 = (const float*)d_in[4];
    const float* bs2 = (const float*)d_in[5];
    const float* Wr1 = (const float*)d_in[6];
    const float* br1 = (const float*)d_in[7];
    const float* Wr2 = (const float*)d_in[8];
    const float* br2 = (const float*)d_in[9];
    const float* Wk1 = (const float*)d_in[10];
    const float* bk1 = (const float*)d_in[11];
    const float* Wk2 = (const float*)d_in[12];
    const float* bk2 = (const float*)d_in[13];

    char* ws = (char*)d_ws;
    size_t off = 0;
    auto alloc = [&](size_t bytes) { char* p = ws + off; off += (bytes + 255) & ~(size_t)255; return p; };
    u16* xh     = (u16*)alloc((size_t)BB * KEXT * 2);
    u16* xl     = (u16*)alloc((size_t)BB * KEXT * 2);
    u16* w1t    = (u16*)alloc((size_t)HH * KEXT * 2);
    u16* wr1h   = (u16*)alloc((size_t)HH * KEXT * 2);
    u16* wr1l   = (u16*)alloc((size_t)HH * KEXT * 2);
    u16* w2t1   = (u16*)alloc((size_t)EE * HH * 2);
    u16* wr2th  = (u16*)alloc((size_t)EE * HH * 2);
    u16* wr2tl  = (u16*)alloc((size_t)EE * HH * 2);
    u16* patTh  = (u16*)alloc((size_t)EE * DD * 2);
    u16* patTl  = (u16*)alloc((size_t)EE * DD * 2);
    u16* ha     = (u16*)alloc((size_t)BB * HH * 2);
    u16* hb     = (u16*)alloc((size_t)BB * HH * 2);
    unsigned* kflags = (unsigned*)alloc((size_t)BB * 4);
    int* cnt      = (int*)alloc(64);

    float* out        = (float*)d_out;
    float* out_gates  = out;
    float* out_idx    = out + (size_t)BB * 4;
    float* out_probs  = out + (size_t)BB * 8;
    float* out_stats  = out + (size_t)BB * 24;

    prep_w<<<(HH*KEXT + 255)/256, 256, 0, stream>>>(Ws1, Wr1, Ws2, Wr2, pat,
        w1t, wr1h, wr1l, w2t1, wr2th, wr2tl, patTh, patTl);

    stats_kernel<<<BB/4, 256, 0, stream>>>(x, Wk1, bk1, Wk2, bk2, out_stats, xh, xl, kflags);

    kmed_kernel<<<1, 1024, 0, stream>>>(kflags, cnt);

    // h1 = relu(x@Ws1 + bs1), plain bf16, bf16 out
    gemm_tile<false, false><<<dim3(8, 128), 256, 0, stream>>>(
        xh, nullptr, w1t, nullptr, bs1, ha, nullptr, 64, KEXT, KEXT);

    // simspec + ss sigmoid -> xh/xl cols 2048..2079
    thinA<<<BB/16, 256, 0, stream>>>(xh, xl, patTh, patTl, ha, w2t1, bs2, xh, xl);

    // h2 = relu(ri@Wr1 + br1), fused 3-term, split-bf16 out (ha=hi, hb=lo)
    gemm_tile<true, true><<<dim3(8, 128), 256, 0, stream>>>(
        xh, xl, wr1h, wr1l, br1, ha, hb, 65, KEXT, KEXT);

    // logits (3-term) + softmax + top4 + gates
    thinB<<<BB/16, 256, 0, stream>>>(ha, hb, wr2th, wr2tl, br2, cnt,
                                     out_gates, out_idx, out_probs);
}

// Round 5
// 645.805 us; speedup vs baseline: 2.6692x; 1.1365x over previous
//
#include <hip/hip_runtime.h>
#include <hip/hip_bf16.h>

typedef unsigned short u16;
typedef __attribute__((ext_vector_type(8))) short bf16x8;
typedef __attribute__((ext_vector_type(8))) unsigned short u16x8;
typedef __attribute__((ext_vector_type(4))) float f32x4;

#define BB 16384
#define DD 2048
#define KEXT 2112   // 2048 x-cols + 16 ss cols + 48 zero pad (33 * 64)
#define HH 1024
#define EE 16
#define TOPN 409

__device__ __forceinline__ u16 f2bf(float f) {
    union { float f; unsigned u; } c; c.f = f;
    unsigned r = c.u + 0x7fffu + ((c.u >> 16) & 1u);
    return (u16)(r >> 16);
}
__device__ __forceinline__ float bf2f(u16 h) {
    union { unsigned u; float f; } c; c.u = ((unsigned)h) << 16; return c.f;
}

__device__ __forceinline__ void ld16_lds(const void* g, void* l) {
    __builtin_amdgcn_global_load_lds(
        (const __attribute__((address_space(1))) unsigned int*)g,
        (__attribute__((address_space(3))) unsigned int*)l, 16, 0, 0);
}

// ---------------- prep_t: coalesced LDS-transpose of Ws1 / Wr1 ----------------
__global__ __launch_bounds__(256)
void prep_t(const float* __restrict__ Ws1, const float* __restrict__ Wr1,
            u16* __restrict__ w1t, u16* __restrict__ wr1h, u16* __restrict__ wr1l)
{
    __shared__ float tile[64][65];
    const int kt = blockIdx.x;       // k-tile (0..32)
    const int nt = blockIdx.y;       // n-tile (0..15)
    const int mat = blockIdx.z;      // 0: Ws1 (32 k-tiles), 1: Wr1 (33 k-tiles)
    if (mat == 0 && kt >= 32) return;
    const int k0 = kt * 64, n0 = nt * 64;
    const float* src = mat ? Wr1 : Ws1;
    const int kmax = mat ? (DD + EE) : DD;
    const int t = threadIdx.x;
    #pragma unroll
    for (int i = 0; i < 16; ++i) {
        int e = i * 256 + t;
        int r = e >> 6, c = e & 63;
        float v = (k0 + r < kmax) ? src[(size_t)(k0 + r) * HH + n0 + c] : 0.0f;
        tile[r][c] = v;
    }
    __syncthreads();
    #pragma unroll
    for (int i = 0; i < 16; ++i) {
        int e = i * 256 + t;
        int rn = e >> 6, ck = e & 63;
        float v = tile[ck][rn];
        size_t oidx = (size_t)(n0 + rn) * KEXT + k0 + ck;
        if (mat == 0) {
            w1t[oidx] = f2bf(v);
        } else {
            u16 h = f2bf(v);
            wr1h[oidx] = h;
            wr1l[oidx] = f2bf(v - bf2f(h));
        }
    }
}

// ---------------- prep_small: thin-GEMM weights (Ws2, Wr2, patterns) ----------------
__global__ __launch_bounds__(256)
void prep_small(const float* __restrict__ Ws2, const float* __restrict__ Wr2,
                const float* __restrict__ pat,
                u16* __restrict__ w2t1, u16* __restrict__ wr2th, u16* __restrict__ wr2tl,
                u16* __restrict__ patTh, u16* __restrict__ patTl)
{
    int idx = blockIdx.x * 256 + threadIdx.x;
    if (idx < EE * HH) {
        int e = idx / HH, n = idx % HH;
        w2t1[idx] = f2bf(Ws2[(size_t)n * EE + e]);
        float v = Wr2[(size_t)n * EE + e];
        u16 h = f2bf(v);
        wr2th[idx] = h;
        wr2tl[idx] = f2bf(v - bf2f(h));
    }
    if (idx < EE * DD) {
        float v = pat[idx];   // pat is [E][D] row-major = B^T layout already
        u16 h = f2bf(v);
        patTh[idx] = h;
        patTl[idx] = f2bf(v - bf2f(h));
    }
}

// ---------------- stats: 1 wave per row, register-resident ----------------
__global__ __launch_bounds__(256)
void stats_kernel(const float* __restrict__ x,
                  const float* __restrict__ Wk1, const float* __restrict__ bk1,
                  const float* __restrict__ Wk2, const float* __restrict__ bk2,
                  float* __restrict__ stats_out, u16* __restrict__ xh, u16* __restrict__ xl,
                  unsigned* __restrict__ kflags)
{
    const int wid = threadIdx.x >> 6;
    const int lane = threadIdx.x & 63;
    const int row = blockIdx.x * 4 + wid;
    const float* xr = x + (size_t)row * DD;

    float v[32];
    #pragma unroll
    for (int s = 0; s < 8; ++s) {
        float4 a = *(const float4*)(xr + s * 256 + lane * 4);
        v[s*4+0]=a.x; v[s*4+1]=a.y; v[s*4+2]=a.z; v[s*4+3]=a.w;
    }

    u16* ph = xh + (size_t)row * KEXT;
    u16* pl = xl + (size_t)row * KEXT;
    #pragma unroll
    for (int s = 0; s < 8; ++s) {
        union { u16 a[4]; unsigned long long q; } H, L;
        #pragma unroll
        for (int c = 0; c < 4; ++c) {
            float f = v[s*4+c];
            u16 h = f2bf(f);
            H.a[c] = h; L.a[c] = f2bf(f - bf2f(h));
        }
        *(unsigned long long*)(ph + s*256 + lane*4) = H.q;
        *(unsigned long long*)(pl + s*256 + lane*4) = L.q;
    }
    // zero the pad/ss columns (thinA later fills 2048..2063 with ss)
    ph[DD + lane] = 0;
    pl[DD + lane] = 0;

    float s1 = 0;
    #pragma unroll
    for (int j = 0; j < 32; ++j) s1 += v[j];
    #pragma unroll
    for (int off = 32; off >= 1; off >>= 1) s1 += __shfl_xor(s1, off);
    const float mean = s1 * (1.0f/2048.0f);

    float s2=0, s3=0, sa=0, sq=0, zc=0, mx=0;
    #pragma unroll
    for (int j = 0; j < 32; ++j) {
        float d = v[j] - mean;
        s2 += d*d; s3 += d*d*d;
        float av = fabsf(v[j]);
        sa += av; sq += v[j]*v[j];
        mx = fmaxf(mx, av);
        zc += (v[j] == 0.0f) ? 1.0f : 0.0f;
    }
    #pragma unroll
    for (int off = 32; off >= 1; off >>= 1) {
        s2 += __shfl_xor(s2, off);
        s3 += __shfl_xor(s3, off);
        sa += __shfl_xor(sa, off);
        sq += __shfl_xor(sq, off);
        zc += __shfl_xor(zc, off);
        mx = fmaxf(mx, __shfl_xor(mx, off));
    }

    #pragma unroll
    for (int j = 0; j < 32; ++j) v[j] = fabsf(v[j]);

    unsigned lo = 0, hi = 0x7F800000u;
    while (lo < hi) {
        unsigned mid = (lo + hi) >> 1;
        float midf = __uint_as_float(mid);
        unsigned cnt = 0;
        #pragma unroll
        for (int j = 0; j < 32; ++j)
            cnt += (unsigned)__popcll(__ballot(v[j] > midf));
        if (cnt < TOPN) hi = mid; else lo = mid + 1;
    }
    const float T = __uint_as_float(lo);

    float cg = 0, sg = 0;
    #pragma unroll
    for (int j = 0; j < 32; ++j) {
        if (v[j] > T) { cg += 1.0f; sg += v[j]; }
    }
    #pragma unroll
    for (int off = 32; off >= 1; off >>= 1) { cg += __shfl_xor(cg, off); sg += __shfl_xor(sg, off); }

    if (lane == 0) {
        float top = sg + ((float)TOPN - cg) * T;
        float var_u = s2 * (1.0f/2047.0f);
        float stdv = sqrtf(var_u + 1e-8f);
        float st0 = zc * (1.0f/2048.0f);
        float st1 = var_u;
        float st2 = mx;
        float st3 = sqrtf(sq);
        float st4 = (s3 * (1.0f/2048.0f)) / (stdv*stdv*stdv);
        float st5 = top / (sa + 1e-8f);
        float* so = stats_out + (size_t)row * 6;
        so[0]=st0; so[1]=st1; so[2]=st2; so[3]=st3; so[4]=st4; so[5]=st5;
        float stv[6] = {st0,st1,st2,st3,st4,st5};
        float o = bk2[0];
        #pragma unroll
        for (int i = 0; i < 16; ++i) {
            float h = bk1[i];
            #pragma unroll
            for (int f = 0; f < 6; ++f) h += stv[f] * Wk1[f*16 + i];
            o += fmaxf(h, 0.0f) * Wk2[i];
        }
        float kr = 1.0f / (1.0f + expf(-o));
        float kv = 1.0f + 3.0f * kr;
        kflags[row] = (kv < 2.0f ? 1u : 0u) | (kv < 3.0f ? 0x10000u : 0u);
    }
}

// ---------------- k-median reduce ----------------
__global__ __launch_bounds__(1024)
void kmed_kernel(const unsigned* __restrict__ kflags, int* __restrict__ counters)
{
    const int t = threadIdx.x;
    unsigned s = 0;
    for (int i = t; i < BB; i += 1024) s += kflags[i];
    #pragma unroll
    for (int off = 32; off >= 1; off >>= 1) s += __shfl_xor(s, off);
    __shared__ unsigned red[16];
    if ((t & 63) == 0) red[t >> 6] = s;
    __syncthreads();
    if (t == 0) {
        unsigned tot = 0;
        #pragma unroll
        for (int w = 0; w < 16; ++w) tot += red[w];
        counters[0] = (int)(tot & 0xFFFFu);
        counters[1] = (int)(tot >> 16);
    }
}

// ---------------- big GEMM: BK=64, XOR-swizzled LDS, relu(A@B^T + bias) -> bf16 ----------------
// chunk c (16B) of row r stored at LDS slot r*8 + (c ^ (r&7)); swizzle applied in the
// GLOBAL address so global_load_lds's fixed base+lane*16 LDS mapping is preserved.
template<bool SPLIT3, bool OSPLIT>
__global__ __launch_bounds__(256)
void gemm_tile(const u16* __restrict__ Ah, const u16* __restrict__ Al,
               const u16* __restrict__ Bh, const u16* __restrict__ Bl,
               const float* __restrict__ bias,
               u16* __restrict__ Oh, u16* __restrict__ Ol,
               int kiters, int stride)
{
    __shared__ u16 AsH[128*64];
    __shared__ u16 BsH[128*64];
    __shared__ u16 AsL[SPLIT3 ? 128*64 : 8];
    __shared__ u16 BsL[SPLIT3 ? 128*64 : 8];
    const int t = threadIdx.x;
    const int m0 = blockIdx.y * 128;
    const int n0 = blockIdx.x * 128;
    const int wid = t >> 6, lane = t & 63, l16 = lane & 15, q = lane >> 4;
    const int wm = (wid & 1) * 64, wn = (wid >> 1) * 64;
    const int x7 = l16 & 7;

    f32x4 acc[4][4] = {};

    for (int it = 0; it < kiters; ++it) {
        const int k0 = it * 64;
        __syncthreads();
        #pragma unroll
        for (int s = 0; s < 4; ++s) {
            int seg = t + s * 256;           // 0..1023 chunk slots
            int row = seg >> 3;
            int c = (seg & 7) ^ (row & 7);   // swizzled k-chunk
            size_t goff = (size_t)k0 + c * 8;
            size_t aoff = (size_t)(m0 + row) * stride + goff;
            size_t boff = (size_t)(n0 + row) * stride + goff;
            ld16_lds(Ah + aoff, (void*)(AsH + seg * 8));
            ld16_lds(Bh + boff, (void*)(BsH + seg * 8));
            if constexpr (SPLIT3) {
                ld16_lds(Al + aoff, (void*)(AsL + seg * 8));
                ld16_lds(Bl + boff, (void*)(BsL + seg * 8));
            }
        }
        __syncthreads();
        #pragma unroll
        for (int h = 0; h < 2; ++h) {
            const int coff = ((4*h + q) ^ x7) * 8;
            bf16x8 afh[4], bfh[4], afl[4], bfl[4];
            #pragma unroll
            for (int i = 0; i < 4; ++i) {
                const int ra = (wm + 16*i + l16) * 64 + coff;
                const int rb = (wn + 16*i + l16) * 64 + coff;
                afh[i] = *(const bf16x8*)(AsH + ra);
                bfh[i] = *(const bf16x8*)(BsH + rb);
                if constexpr (SPLIT3) {
                    afl[i] = *(const bf16x8*)(AsL + ra);
                    bfl[i] = *(const bf16x8*)(BsL + rb);
                }
            }
            #pragma unroll
            for (int i = 0; i < 4; ++i)
                #pragma unroll
                for (int j = 0; j < 4; ++j) {
                    acc[i][j] = __builtin_amdgcn_mfma_f32_16x16x32_bf16(afh[i], bfh[j], acc[i][j], 0, 0, 0);
                    if constexpr (SPLIT3) {
                        acc[i][j] = __builtin_amdgcn_mfma_f32_16x16x32_bf16(afh[i], bfl[j], acc[i][j], 0, 0, 0);
                        acc[i][j] = __builtin_amdgcn_mfma_f32_16x16x32_bf16(afl[i], bfh[j], acc[i][j], 0, 0, 0);
                    }
                }
        }
    }
    #pragma unroll
    for (int j = 0; j < 4; ++j) {
        int col = n0 + wn + 16*j + l16;
        float bv = bias[col];
        #pragma unroll
        for (int i = 0; i < 4; ++i)
            #pragma unroll
            for (int r = 0; r < 4; ++r) {
                int row = m0 + wm + 16*i + q*4 + r;
                float vv = acc[i][j][r] + bv;
                vv = vv > 0.0f ? vv : 0.0f;
                u16 h = f2bf(vv);
                Oh[(size_t)row * HH + col] = h;
                if constexpr (OSPLIT) Ol[(size_t)row * HH + col] = f2bf(vv - bf2f(h));
            }
    }
}

// ---------------- thinA: simspec = x@pat^T (3-term) + h1@Ws2; ss epilogue -> xh/xl cols ----------------
__global__ __launch_bounds__(256)
void thinA(const u16* __restrict__ xh, const u16* __restrict__ xl,
           const u16* __restrict__ patTh, const u16* __restrict__ patTl,
           const u16* __restrict__ ha, const u16* __restrict__ w2t,
           const float* __restrict__ bs2,
           u16* __restrict__ xh_w, u16* __restrict__ xl_w)
{
    const int t = threadIdx.x;
    const int wid = t >> 6, lane = t & 63, l16 = lane & 15, q = lane >> 4;
    const int m0 = blockIdx.x * 16;
    f32x4 acc = {};
    // sims: 3-term split over K=2048
    for (int it = wid; it < 64; it += 4) {
        const int k0 = it * 32;
        bf16x8 a0 = *(const bf16x8*)(xh + (size_t)(m0 + l16) * KEXT + k0 + q*8);
        bf16x8 a1 = *(const bf16x8*)(xl + (size_t)(m0 + l16) * KEXT + k0 + q*8);
        bf16x8 b0 = *(const bf16x8*)(patTh + (size_t)l16 * DD + k0 + q*8);
        bf16x8 b1 = *(const bf16x8*)(patTl + (size_t)l16 * DD + k0 + q*8);
        acc = __builtin_amdgcn_mfma_f32_16x16x32_bf16(a0, b0, acc, 0, 0, 0);
        acc = __builtin_amdgcn_mfma_f32_16x16x32_bf16(a0, b1, acc, 0, 0, 0);
        acc = __builtin_amdgcn_mfma_f32_16x16x32_bf16(a1, b0, acc, 0, 0, 0);
    }
    // spec: h1 @ Ws2^T over K=1024
    for (int it = wid; it < 32; it += 4) {
        const int k0 = it * 32;
        bf16x8 a = *(const bf16x8*)(ha + (size_t)(m0 + l16) * HH + k0 + q*8);
        bf16x8 b = *(const bf16x8*)(w2t + (size_t)l16 * HH + k0 + q*8);
        acc = __builtin_amdgcn_mfma_f32_16x16x32_bf16(a, b, acc, 0, 0, 0);
    }
    __shared__ f32x4 red[4][64];
    red[wid][lane] = acc;
    __syncthreads();
    if (wid == 0) {
        f32x4 v = red[0][lane];
        #pragma unroll
        for (int w = 1; w < 4; ++w) {
            f32x4 o = red[w][lane];
            v[0]+=o[0]; v[1]+=o[1]; v[2]+=o[2]; v[3]+=o[3];
        }
        const float b2 = bs2[l16];
        #pragma unroll
        for (int r = 0; r < 4; ++r) {
            int row = m0 + q*4 + r;
            float ssv = 1.0f / (1.0f + expf(-(v[r] + b2)));
            u16 h = f2bf(ssv);
            u16 lo = f2bf(ssv - bf2f(h));
            xh_w[(size_t)row * KEXT + DD + l16] = h;
            xl_w[(size_t)row * KEXT + DD + l16] = lo;
        }
    }
}

// ---------------- thinB: logits = h2@Wr2 (3-term) + br2; softmax+top4+gates ----------------
__global__ __launch_bounds__(256)
void thinB(const u16* __restrict__ hh, const u16* __restrict__ hl,
           const u16* __restrict__ wr2th, const u16* __restrict__ wr2tl,
           const float* __restrict__ br2, const int* __restrict__ counters,
           float* __restrict__ out_gates, float* __restrict__ out_idx,
           float* __restrict__ out_probs)
{
    const int t = threadIdx.x;
    const int wid = t >> 6, lane = t & 63, l16 = lane & 15, q = lane >> 4;
    const int m0 = blockIdx.x * 16;
    f32x4 acc = {};
    for (int it = wid; it < 32; it += 4) {
        const int k0 = it * 32;
        bf16x8 a0 = *(const bf16x8*)(hh + (size_t)(m0 + l16) * HH + k0 + q*8);
        bf16x8 a1 = *(const bf16x8*)(hl + (size_t)(m0 + l16) * HH + k0 + q*8);
        bf16x8 b0 = *(const bf16x8*)(wr2th + (size_t)l16 * HH + k0 + q*8);
        bf16x8 b1 = *(const bf16x8*)(wr2tl + (size_t)l16 * HH + k0 + q*8);
        acc = __builtin_amdgcn_mfma_f32_16x16x32_bf16(a0, b0, acc, 0, 0, 0);
        acc = __builtin_amdgcn_mfma_f32_16x16x32_bf16(a0, b1, acc, 0, 0, 0);
        acc = __builtin_amdgcn_mfma_f32_16x16x32_bf16(a1, b0, acc, 0, 0, 0);
    }
    __shared__ f32x4 red[4][64];
    red[wid][lane] = acc;
    __syncthreads();
    if (wid != 0) return;
    f32x4 v = red[0][lane];
    #pragma unroll
    for (int w = 1; w < 4; ++w) {
        f32x4 o = red[w][lane];
        v[0]+=o[0]; v[1]+=o[1]; v[2]+=o[2]; v[3]+=o[3];
    }
    const float b2 = br2[l16];
    const int c2 = counters[0], c3 = counters[1];
    const int k = (c2 >= 8192) ? 1 : ((c3 >= 8192) ? 2 : 3);
    #pragma unroll
    for (int r = 0; r < 4; ++r) {
        const int row = m0 + q*4 + r;
        float lg = v[r] + b2;
        float mxv = lg;
        #pragma unroll
        for (int off = 1; off < 16; off <<= 1) mxv = fmaxf(mxv, __shfl_xor(mxv, off));
        float e = expf(lg - mxv);
        float den = e;
        #pragma unroll
        for (int off = 1; off < 16; off <<= 1) den += __shfl_xor(den, off);
        float p = e / den;
        out_probs[(size_t)row * EE + l16] = p;
        int kcur = (int)((__float_as_uint(p) & ~15u) | (15u - (unsigned)l16));
        float tv[4]; int ti[4];
        #pragma unroll
        for (int s = 0; s < 4; ++s) {
            int kk = kcur;
            #pragma unroll
            for (int off = 1; off < 16; off <<= 1) kk = max(kk, __shfl_xor(kk, off));
            int widx = 15 - (kk & 15);
            ti[s] = widx;
            tv[s] = __shfl(p, q * 16 + widx);
            if (l16 == widx) kcur = 0;
        }
        float den2 = 0.0f;
        float g[4];
        #pragma unroll
        for (int s = 0; s < 4; ++s) {
            g[s] = expf(tv[s] - tv[0]);
            if (s < k) den2 += g[s];
        }
        if (l16 < 4) {
            out_gates[(size_t)row * 4 + l16] = (l16 < k) ? g[l16] / den2 : 0.0f;
            out_idx[(size_t)row * 4 + l16] = (float)ti[l16];
        }
    }
}

// ---------------- host launch ----------------
extern "C" void kernel_launch(void* const* d_in, const int* in_sizes, int n_in,
                              void* d_out, int out_size, void* d_ws, size_t ws_size,
                              hipStream_t stream) {
    const float* x   = (const float*)d_in[0];
    const float* pat = (const float*)d_in[1];
    const float* Ws1 = (const float*)d_in[2];
    const float* bs1 = (const float*)d_in[3];
    const float* Ws2 = (const float*)d_in[4];
    const float* bs2 = (const float*)d_in[5];
    const float* Wr1 = (const float*)d_in[6];
    const float* br1 = (const float*)d_in[7];
    const float* Wr2 = (const float*)d_in[8];
    const float* br2 = (const float*)d_in[9];
    const float* Wk1 = (const float*)d_in[10];
    const float* bk1 = (const float*)d_in[11];
    const float* Wk2 = (const float*)d_in[12];
    const float* bk2 = (const float*)d_in[13];

    char* ws = (char*)d_ws;
    size_t off = 0;
    auto alloc = [&](size_t bytes) { char* p = ws + off; off += (bytes + 255) & ~(size_t)255; return p; };
    u16* xh     = (u16*)alloc((size_t)BB * KEXT * 2);
    u16* xl     = (u16*)alloc((size_t)BB * KEXT * 2);
    u16* w1t    = (u16*)alloc((size_t)HH * KEXT * 2);
    u16* wr1h   = (u16*)alloc((size_t)HH * KEXT * 2);
    u16* wr1l   = (u16*)alloc((size_t)HH * KEXT * 2);
    u16* w2t1   = (u16*)alloc((size_t)EE * HH * 2);
    u16* wr2th  = (u16*)alloc((size_t)EE * HH * 2);
    u16* wr2tl  = (u16*)alloc((size_t)EE * HH * 2);
    u16* patTh  = (u16*)alloc((size_t)EE * DD * 2);
    u16* patTl  = (u16*)alloc((size_t)EE * DD * 2);
    u16* ha     = (u16*)alloc((size_t)BB * HH * 2);
    u16* hb     = (u16*)alloc((size_t)BB * HH * 2);
    unsigned* kflags = (unsigned*)alloc((size_t)BB * 4);
    int* cnt      = (int*)alloc(64);

    float* out        = (float*)d_out;
    float* out_gates  = out;
    float* out_idx    = out + (size_t)BB * 4;
    float* out_probs  = out + (size_t)BB * 8;
    float* out_stats  = out + (size_t)BB * 24;

    prep_t<<<dim3(33, 16, 2), 256, 0, stream>>>(Ws1, Wr1, w1t, wr1h, wr1l);

    prep_small<<<(EE*DD + 255)/256, 256, 0, stream>>>(Ws2, Wr2, pat,
        w2t1, wr2th, wr2tl, patTh, patTl);

    stats_kernel<<<BB/4, 256, 0, stream>>>(x, Wk1, bk1, Wk2, bk2, out_stats, xh, xl, kflags);

    kmed_kernel<<<1, 1024, 0, stream>>>(kflags, cnt);

    // h1 = relu(x@Ws1 + bs1), plain bf16, bf16 out (K=2048 -> 32 BK64 iters)
    gemm_tile<false, false><<<dim3(8, 128), 256, 0, stream>>>(
        xh, nullptr, w1t, nullptr, bs1, ha, nullptr, 32, KEXT);

    // simspec + ss sigmoid -> xh/xl cols 2048..2063
    thinA<<<BB/16, 256, 0, stream>>>(xh, xl, patTh, patTl, ha, w2t1, bs2, xh, xl);

    // h2 = relu(ri@Wr1 + br1), fused 3-term, split-bf16 out (K=2112 -> 33 BK64 iters)
    gemm_tile<true, true><<<dim3(8, 128), 256, 0, stream>>>(
        xh, xl, wr1h, wr1l, br1, ha, hb, 33, KEXT);

    // logits (3-term) + softmax + top4 + gates
    thinB<<<BB/16, 256, 0, stream>>>(ha, hb, wr2th, wr2tl, br2, cnt,
                                     out_gates, out_idx, out_probs);
}

// Round 6
// 628.191 us; speedup vs baseline: 2.7441x; 1.0280x over previous
//
#include <hip/hip_runtime.h>
#include <hip/hip_bf16.h>

typedef unsigned short u16;
typedef __attribute__((ext_vector_type(8))) short bf16x8;
typedef __attribute__((ext_vector_type(8))) unsigned short u16x8;
typedef __attribute__((ext_vector_type(4))) float f32x4;

#define BB 16384
#define DD 2048
#define KEXT 2112   // 2048 x-cols + 16 ss cols + 48 zero pad (33 * 64)
#define HH 1024
#define EE 16
#define TOPN 409

__device__ __forceinline__ u16 f2bf(float f) {
    union { float f; unsigned u; } c; c.f = f;
    unsigned r = c.u + 0x7fffu + ((c.u >> 16) & 1u);
    return (u16)(r >> 16);
}
__device__ __forceinline__ float bf2f(u16 h) {
    union { unsigned u; float f; } c; c.u = ((unsigned)h) << 16; return c.f;
}

__device__ __forceinline__ void ld16_lds(const void* g, void* l) {
    __builtin_amdgcn_global_load_lds(
        (const __attribute__((address_space(1))) unsigned int*)g,
        (__attribute__((address_space(3))) unsigned int*)l, 16, 0, 0);
}

// ---------------- prep_t: coalesced LDS-transpose of Ws1 / Wr1 ----------------
__global__ __launch_bounds__(256)
void prep_t(const float* __restrict__ Ws1, const float* __restrict__ Wr1,
            u16* __restrict__ w1t, u16* __restrict__ wr1h, u16* __restrict__ wr1l)
{
    __shared__ float tile[64][65];
    const int kt = blockIdx.x;       // k-tile (0..32)
    const int nt = blockIdx.y;       // n-tile (0..15)
    const int mat = blockIdx.z;      // 0: Ws1 (32 k-tiles), 1: Wr1 (33 k-tiles)
    if (mat == 0 && kt >= 32) return;
    const int k0 = kt * 64, n0 = nt * 64;
    const float* src = mat ? Wr1 : Ws1;
    const int kmax = mat ? (DD + EE) : DD;
    const int t = threadIdx.x;
    #pragma unroll
    for (int i = 0; i < 16; ++i) {
        int e = i * 256 + t;
        int r = e >> 6, c = e & 63;
        float v = (k0 + r < kmax) ? src[(size_t)(k0 + r) * HH + n0 + c] : 0.0f;
        tile[r][c] = v;
    }
    __syncthreads();
    #pragma unroll
    for (int i = 0; i < 16; ++i) {
        int e = i * 256 + t;
        int rn = e >> 6, ck = e & 63;
        float v = tile[ck][rn];
        size_t oidx = (size_t)(n0 + rn) * KEXT + k0 + ck;
        if (mat == 0) {
            w1t[oidx] = f2bf(v);
        } else {
            u16 h = f2bf(v);
            wr1h[oidx] = h;
            wr1l[oidx] = f2bf(v - bf2f(h));
        }
    }
}

// ---------------- prep_small: thin-GEMM weights (Ws2, Wr2, patterns) ----------------
__global__ __launch_bounds__(256)
void prep_small(const float* __restrict__ Ws2, const float* __restrict__ Wr2,
                const float* __restrict__ pat,
                u16* __restrict__ w2t1, u16* __restrict__ wr2th, u16* __restrict__ wr2tl,
                u16* __restrict__ patTh, u16* __restrict__ patTl)
{
    int idx = blockIdx.x * 256 + threadIdx.x;
    if (idx < EE * HH) {
        int e = idx / HH, n = idx % HH;
        w2t1[idx] = f2bf(Ws2[(size_t)n * EE + e]);
        float v = Wr2[(size_t)n * EE + e];
        u16 h = f2bf(v);
        wr2th[idx] = h;
        wr2tl[idx] = f2bf(v - bf2f(h));
    }
    if (idx < EE * DD) {
        float v = pat[idx];   // pat is [E][D] row-major = B^T layout already
        u16 h = f2bf(v);
        patTh[idx] = h;
        patTl[idx] = f2bf(v - bf2f(h));
    }
}

// ---------------- stats: 1 wave per row, register-resident ----------------
__global__ __launch_bounds__(256)
void stats_kernel(const float* __restrict__ x,
                  const float* __restrict__ Wk1, const float* __restrict__ bk1,
                  const float* __restrict__ Wk2, const float* __restrict__ bk2,
                  float* __restrict__ stats_out, u16* __restrict__ xh, u16* __restrict__ xl,
                  unsigned* __restrict__ kflags)
{
    const int wid = threadIdx.x >> 6;
    const int lane = threadIdx.x & 63;
    const int row = blockIdx.x * 4 + wid;
    const float* xr = x + (size_t)row * DD;

    float v[32];
    #pragma unroll
    for (int s = 0; s < 8; ++s) {
        float4 a = *(const float4*)(xr + s * 256 + lane * 4);
        v[s*4+0]=a.x; v[s*4+1]=a.y; v[s*4+2]=a.z; v[s*4+3]=a.w;
    }

    u16* ph = xh + (size_t)row * KEXT;
    u16* pl = xl + (size_t)row * KEXT;
    #pragma unroll
    for (int s = 0; s < 8; ++s) {
        union { u16 a[4]; unsigned long long q; } H, L;
        #pragma unroll
        for (int c = 0; c < 4; ++c) {
            float f = v[s*4+c];
            u16 h = f2bf(f);
            H.a[c] = h; L.a[c] = f2bf(f - bf2f(h));
        }
        *(unsigned long long*)(ph + s*256 + lane*4) = H.q;
        *(unsigned long long*)(pl + s*256 + lane*4) = L.q;
    }
    // zero the pad/ss columns (thinA later fills 2048..2063 with ss)
    ph[DD + lane] = 0;
    pl[DD + lane] = 0;

    float s1 = 0;
    #pragma unroll
    for (int j = 0; j < 32; ++j) s1 += v[j];
    #pragma unroll
    for (int off = 32; off >= 1; off >>= 1) s1 += __shfl_xor(s1, off);
    const float mean = s1 * (1.0f/2048.0f);

    float s2=0, s3=0, sa=0, sq=0, zc=0, mx=0;
    #pragma unroll
    for (int j = 0; j < 32; ++j) {
        float d = v[j] - mean;
        s2 += d*d; s3 += d*d*d;
        float av = fabsf(v[j]);
        sa += av; sq += v[j]*v[j];
        mx = fmaxf(mx, av);
        zc += (v[j] == 0.0f) ? 1.0f : 0.0f;
    }
    #pragma unroll
    for (int off = 32; off >= 1; off >>= 1) {
        s2 += __shfl_xor(s2, off);
        s3 += __shfl_xor(s3, off);
        sa += __shfl_xor(sa, off);
        sq += __shfl_xor(sq, off);
        zc += __shfl_xor(zc, off);
        mx = fmaxf(mx, __shfl_xor(mx, off));
    }

    #pragma unroll
    for (int j = 0; j < 32; ++j) v[j] = fabsf(v[j]);

    unsigned lo = 0, hi = 0x7F800000u;
    while (lo < hi) {
        unsigned mid = (lo + hi) >> 1;
        float midf = __uint_as_float(mid);
        unsigned cnt = 0;
        #pragma unroll
        for (int j = 0; j < 32; ++j)
            cnt += (unsigned)__popcll(__ballot(v[j] > midf));
        if (cnt < TOPN) hi = mid; else lo = mid + 1;
    }
    const float T = __uint_as_float(lo);

    float cg = 0, sg = 0;
    #pragma unroll
    for (int j = 0; j < 32; ++j) {
        if (v[j] > T) { cg += 1.0f; sg += v[j]; }
    }
    #pragma unroll
    for (int off = 32; off >= 1; off >>= 1) { cg += __shfl_xor(cg, off); sg += __shfl_xor(sg, off); }

    if (lane == 0) {
        float top = sg + ((float)TOPN - cg) * T;
        float var_u = s2 * (1.0f/2047.0f);
        float stdv = sqrtf(var_u + 1e-8f);
        float st0 = zc * (1.0f/2048.0f);
        float st1 = var_u;
        float st2 = mx;
        float st3 = sqrtf(sq);
        float st4 = (s3 * (1.0f/2048.0f)) / (stdv*stdv*stdv);
        float st5 = top / (sa + 1e-8f);
        float* so = stats_out + (size_t)row * 6;
        so[0]=st0; so[1]=st1; so[2]=st2; so[3]=st3; so[4]=st4; so[5]=st5;
        float stv[6] = {st0,st1,st2,st3,st4,st5};
        float o = bk2[0];
        #pragma unroll
        for (int i = 0; i < 16; ++i) {
            float h = bk1[i];
            #pragma unroll
            for (int f = 0; f < 6; ++f) h += stv[f] * Wk1[f*16 + i];
            o += fmaxf(h, 0.0f) * Wk2[i];
        }
        float kr = 1.0f / (1.0f + expf(-o));
        float kv = 1.0f + 3.0f * kr;
        kflags[row] = (kv < 2.0f ? 1u : 0u) | (kv < 3.0f ? 0x10000u : 0u);
    }
}

// ---------------- k-median reduce ----------------
__global__ __launch_bounds__(1024)
void kmed_kernel(const unsigned* __restrict__ kflags, int* __restrict__ counters)
{
    const int t = threadIdx.x;
    unsigned s = 0;
    for (int i = t; i < BB; i += 1024) s += kflags[i];
    #pragma unroll
    for (int off = 32; off >= 1; off >>= 1) s += __shfl_xor(s, off);
    __shared__ unsigned red[16];
    if ((t & 63) == 0) red[t >> 6] = s;
    __syncthreads();
    if (t == 0) {
        unsigned tot = 0;
        #pragma unroll
        for (int w = 0; w < 16; ++w) tot += red[w];
        counters[0] = (int)(tot & 0xFFFFu);
        counters[1] = (int)(tot >> 16);
    }
}

// ---------------- big GEMM: BK=64, XOR-swizzled LDS, XCD-aware block swizzle ----------------
// 1D grid of 1024 blocks. Under round-robin block->XCD dispatch (xcd = id%8),
// each XCD owns a contiguous 16-row-block m-slice and iterates n fastest, so the
// 8 blocks sharing an A row-tile are temporally adjacent on the SAME XCD -> A-tile
// is fetched into that XCD's L2 once instead of 8 HBM fetches across 8 XCDs.
template<bool SPLIT3, bool OSPLIT>
__global__ __launch_bounds__(256)
void gemm_tile(const u16* __restrict__ Ah, const u16* __restrict__ Al,
               const u16* __restrict__ Bh, const u16* __restrict__ Bl,
               const float* __restrict__ bias,
               u16* __restrict__ Oh, u16* __restrict__ Ol,
               int kiters, int stride)
{
    __shared__ u16 AsH[128*64];
    __shared__ u16 BsH[128*64];
    __shared__ u16 AsL[SPLIT3 ? 128*64 : 8];
    __shared__ u16 BsL[SPLIT3 ? 128*64 : 8];
    const int t = threadIdx.x;
    const int id = blockIdx.x;
    const int xcd = id & 7;
    const int jj = id >> 3;
    const int nblk = jj & 7;         // n varies fastest within an XCD
    const int mgrp = jj >> 3;        // 0..15
    const int m0 = (xcd * 16 + mgrp) * 128;
    const int n0 = nblk * 128;
    const int wid = t >> 6, lane = t & 63, l16 = lane & 15, q = lane >> 4;
    const int wm = (wid & 1) * 64, wn = (wid >> 1) * 64;
    const int x7 = l16 & 7;

    f32x4 acc[4][4] = {};

    for (int it = 0; it < kiters; ++it) {
        const int k0 = it * 64;
        __syncthreads();
        #pragma unroll
        for (int s = 0; s < 4; ++s) {
            int seg = t + s * 256;           // 0..1023 chunk slots
            int row = seg >> 3;
            int c = (seg & 7) ^ (row & 7);   // swizzled k-chunk
            size_t goff = (size_t)k0 + c * 8;
            size_t aoff = (size_t)(m0 + row) * stride + goff;
            size_t boff = (size_t)(n0 + row) * stride + goff;
            ld16_lds(Ah + aoff, (void*)(AsH + seg * 8));
            ld16_lds(Bh + boff, (void*)(BsH + seg * 8));
            if constexpr (SPLIT3) {
                ld16_lds(Al + aoff, (void*)(AsL + seg * 8));
                ld16_lds(Bl + boff, (void*)(BsL + seg * 8));
            }
        }
        __syncthreads();
        #pragma unroll
        for (int h = 0; h < 2; ++h) {
            const int coff = ((4*h + q) ^ x7) * 8;
            bf16x8 afh[4], bfh[4], afl[4], bfl[4];
            #pragma unroll
            for (int i = 0; i < 4; ++i) {
                const int ra = (wm + 16*i + l16) * 64 + coff;
                const int rb = (wn + 16*i + l16) * 64 + coff;
                afh[i] = *(const bf16x8*)(AsH + ra);
                bfh[i] = *(const bf16x8*)(BsH + rb);
                if constexpr (SPLIT3) {
                    afl[i] = *(const bf16x8*)(AsL + ra);
                    bfl[i] = *(const bf16x8*)(BsL + rb);
                }
            }
            #pragma unroll
            for (int i = 0; i < 4; ++i)
                #pragma unroll
                for (int j = 0; j < 4; ++j) {
                    acc[i][j] = __builtin_amdgcn_mfma_f32_16x16x32_bf16(afh[i], bfh[j], acc[i][j], 0, 0, 0);
                    if constexpr (SPLIT3) {
                        acc[i][j] = __builtin_amdgcn_mfma_f32_16x16x32_bf16(afh[i], bfl[j], acc[i][j], 0, 0, 0);
                        acc[i][j] = __builtin_amdgcn_mfma_f32_16x16x32_bf16(afl[i], bfh[j], acc[i][j], 0, 0, 0);
                    }
                }
        }
    }
    #pragma unroll
    for (int j = 0; j < 4; ++j) {
        int col = n0 + wn + 16*j + l16;
        float bv = bias[col];
        #pragma unroll
        for (int i = 0; i < 4; ++i)
            #pragma unroll
            for (int r = 0; r < 4; ++r) {
                int row = m0 + wm + 16*i + q*4 + r;
                float vv = acc[i][j][r] + bv;
                vv = vv > 0.0f ? vv : 0.0f;
                u16 h = f2bf(vv);
                Oh[(size_t)row * HH + col] = h;
                if constexpr (OSPLIT) Ol[(size_t)row * HH + col] = f2bf(vv - bf2f(h));
            }
    }
}

// ---------------- thinA: simspec = x@pat^T (3-term) + h1@Ws2; ss epilogue -> xh/xl cols ----------------
__global__ __launch_bounds__(256)
void thinA(const u16* __restrict__ xh, const u16* __restrict__ xl,
           const u16* __restrict__ patTh, const u16* __restrict__ patTl,
           const u16* __restrict__ ha, const u16* __restrict__ w2t,
           const float* __restrict__ bs2,
           u16* __restrict__ xh_w, u16* __restrict__ xl_w)
{
    const int t = threadIdx.x;
    const int wid = t >> 6, lane = t & 63, l16 = lane & 15, q = lane >> 4;
    const int m0 = blockIdx.x * 16;
    f32x4 acc = {};
    // sims: 3-term split over K=2048
    for (int it = wid; it < 64; it += 4) {
        const int k0 = it * 32;
        bf16x8 a0 = *(const bf16x8*)(xh + (size_t)(m0 + l16) * KEXT + k0 + q*8);
        bf16x8 a1 = *(const bf16x8*)(xl + (size_t)(m0 + l16) * KEXT + k0 + q*8);
        bf16x8 b0 = *(const bf16x8*)(patTh + (size_t)l16 * DD + k0 + q*8);
        bf16x8 b1 = *(const bf16x8*)(patTl + (size_t)l16 * DD + k0 + q*8);
        acc = __builtin_amdgcn_mfma_f32_16x16x32_bf16(a0, b0, acc, 0, 0, 0);
        acc = __builtin_amdgcn_mfma_f32_16x16x32_bf16(a0, b1, acc, 0, 0, 0);
        acc = __builtin_amdgcn_mfma_f32_16x16x32_bf16(a1, b0, acc, 0, 0, 0);
    }
    // spec: h1 @ Ws2^T over K=1024
    for (int it = wid; it < 32; it += 4) {
        const int k0 = it * 32;
        bf16x8 a = *(const bf16x8*)(ha + (size_t)(m0 + l16) * HH + k0 + q*8);
        bf16x8 b = *(const bf16x8*)(w2t + (size_t)l16 * HH + k0 + q*8);
        acc = __builtin_amdgcn_mfma_f32_16x16x32_bf16(a, b, acc, 0, 0, 0);
    }
    __shared__ f32x4 red[4][64];
    red[wid][lane] = acc;
    __syncthreads();
    if (wid == 0) {
        f32x4 v = red[0][lane];
        #pragma unroll
        for (int w = 1; w < 4; ++w) {
            f32x4 o = red[w][lane];
            v[0]+=o[0]; v[1]+=o[1]; v[2]+=o[2]; v[3]+=o[3];
        }
        const float b2 = bs2[l16];
        #pragma unroll
        for (int r = 0; r < 4; ++r) {
            int row = m0 + q*4 + r;
            float ssv = 1.0f / (1.0f + expf(-(v[r] + b2)));
            u16 h = f2bf(ssv);
            u16 lo = f2bf(ssv - bf2f(h));
            xh_w[(size_t)row * KEXT + DD + l16] = h;
            xl_w[(size_t)row * KEXT + DD + l16] = lo;
        }
    }
}

// ---------------- thinB: logits = h2@Wr2 (3-term) + br2; softmax+top4+gates ----------------
__global__ __launch_bounds__(256)
void thinB(const u16* __restrict__ hh, const u16* __restrict__ hl,
           const u16* __restrict__ wr2th, const u16* __restrict__ wr2tl,
           const float* __restrict__ br2, const int* __restrict__ counters,
           float* __restrict__ out_gates, float* __restrict__ out_idx,
           float* __restrict__ out_probs)
{
    const int t = threadIdx.x;
    const int wid = t >> 6, lane = t & 63, l16 = lane & 15, q = lane >> 4;
    const int m0 = blockIdx.x * 16;
    f32x4 acc = {};
    for (int it = wid; it < 32; it += 4) {
        const int k0 = it * 32;
        bf16x8 a0 = *(const bf16x8*)(hh + (size_t)(m0 + l16) * HH + k0 + q*8);
        bf16x8 a1 = *(const bf16x8*)(hl + (size_t)(m0 + l16) * HH + k0 + q*8);
        bf16x8 b0 = *(const bf16x8*)(wr2th + (size_t)l16 * HH + k0 + q*8);
        bf16x8 b1 = *(const bf16x8*)(wr2tl + (size_t)l16 * HH + k0 + q*8);
        acc = __builtin_amdgcn_mfma_f32_16x16x32_bf16(a0, b0, acc, 0, 0, 0);
        acc = __builtin_amdgcn_mfma_f32_16x16x32_bf16(a0, b1, acc, 0, 0, 0);
        acc = __builtin_amdgcn_mfma_f32_16x16x32_bf16(a1, b0, acc, 0, 0, 0);
    }
    __shared__ f32x4 red[4][64];
    red[wid][lane] = acc;
    __syncthreads();
    if (wid != 0) return;
    f32x4 v = red[0][lane];
    #pragma unroll
    for (int w = 1; w < 4; ++w) {
        f32x4 o = red[w][lane];
        v[0]+=o[0]; v[1]+=o[1]; v[2]+=o[2]; v[3]+=o[3];
    }
    const float b2 = br2[l16];
    const int c2 = counters[0], c3 = counters[1];
    const int k = (c2 >= 8192) ? 1 : ((c3 >= 8192) ? 2 : 3);
    #pragma unroll
    for (int r = 0; r < 4; ++r) {
        const int row = m0 + q*4 + r;
        float lg = v[r] + b2;
        float mxv = lg;
        #pragma unroll
        for (int off = 1; off < 16; off <<= 1) mxv = fmaxf(mxv, __shfl_xor(mxv, off));
        float e = expf(lg - mxv);
        float den = e;
        #pragma unroll
        for (int off = 1; off < 16; off <<= 1) den += __shfl_xor(den, off);
        float p = e / den;
        out_probs[(size_t)row * EE + l16] = p;
        int kcur = (int)((__float_as_uint(p) & ~15u) | (15u - (unsigned)l16));
        float tv[4]; int ti[4];
        #pragma unroll
        for (int s = 0; s < 4; ++s) {
            int kk = kcur;
            #pragma unroll
            for (int off = 1; off < 16; off <<= 1) kk = max(kk, __shfl_xor(kk, off));
            int widx = 15 - (kk & 15);
            ti[s] = widx;
            tv[s] = __shfl(p, q * 16 + widx);
            if (l16 == widx) kcur = 0;
        }
        float den2 = 0.0f;
        float g[4];
        #pragma unroll
        for (int s = 0; s < 4; ++s) {
            g[s] = expf(tv[s] - tv[0]);
            if (s < k) den2 += g[s];
        }
        if (l16 < 4) {
            out_gates[(size_t)row * 4 + l16] = (l16 < k) ? g[l16] / den2 : 0.0f;
            out_idx[(size_t)row * 4 + l16] = (float)ti[l16];
        }
    }
}

// ---------------- host launch ----------------
extern "C" void kernel_launch(void* const* d_in, const int* in_sizes, int n_in,
                              void* d_out, int out_size, void* d_ws, size_t ws_size,
                              hipStream_t stream) {
    const float* x   = (const float*)d_in[0];
    const float* pat = (const float*)d_in[1];
    const float* Ws1 = (const float*)d_in[2];
    const float* bs1 = (const float*)d_in[3];
    const float* Ws2 = (const float*)d_in[4];
    const float* bs2 = (const float*)d_in[5];
    const float* Wr1 = (const float*)d_in[6];
    const float* br1 = (const float*)d_in[7];
    const float* Wr2 = (const float*)d_in[8];
    const float* br2 = (const float*)d_in[9];
    const float* Wk1 = (const float*)d_in[10];
    const float* bk1 = (const float*)d_in[11];
    const float* Wk2 = (const float*)d_in[12];
    const float* bk2 = (const float*)d_in[13];

    char* ws = (char*)d_ws;
    size_t off = 0;
    auto alloc = [&](size_t bytes) { char* p = ws + off; off += (bytes + 255) & ~(size_t)255; return p; };
    u16* xh     = (u16*)alloc((size_t)BB * KEXT * 2);
    u16* xl     = (u16*)alloc((size_t)BB * KEXT * 2);
    u16* w1t    = (u16*)alloc((size_t)HH * KEXT * 2);
    u16* wr1h   = (u16*)alloc((size_t)HH * KEXT * 2);
    u16* wr1l   = (u16*)alloc((size_t)HH * KEXT * 2);
    u16* w2t1   = (u16*)alloc((size_t)EE * HH * 2);
    u16* wr2th  = (u16*)alloc((size_t)EE * HH * 2);
    u16* wr2tl  = (u16*)alloc((size_t)EE * HH * 2);
    u16* patTh  = (u16*)alloc((size_t)EE * DD * 2);
    u16* patTl  = (u16*)alloc((size_t)EE * DD * 2);
    u16* ha     = (u16*)alloc((size_t)BB * HH * 2);
    u16* hb     = (u16*)alloc((size_t)BB * HH * 2);
    unsigned* kflags = (unsigned*)alloc((size_t)BB * 4);
    int* cnt      = (int*)alloc(64);

    float* out        = (float*)d_out;
    float* out_gates  = out;
    float* out_idx    = out + (size_t)BB * 4;
    float* out_probs  = out + (size_t)BB * 8;
    float* out_stats  = out + (size_t)BB * 24;

    prep_t<<<dim3(33, 16, 2), 256, 0, stream>>>(Ws1, Wr1, w1t, wr1h, wr1l);

    prep_small<<<(EE*DD + 255)/256, 256, 0, stream>>>(Ws2, Wr2, pat,
        w2t1, wr2th, wr2tl, patTh, patTl);

    stats_kernel<<<BB/4, 256, 0, stream>>>(x, Wk1, bk1, Wk2, bk2, out_stats, xh, xl, kflags);

    kmed_kernel<<<1, 1024, 0, stream>>>(kflags, cnt);

    // h1 = relu(x@Ws1 + bs1), plain bf16, bf16 out (K=2048 -> 32 BK64 iters)
    gemm_tile<false, false><<<1024, 256, 0, stream>>>(
        xh, nullptr, w1t, nullptr, bs1, ha, nullptr, 32, KEXT);

    // simspec + ss sigmoid -> xh/xl cols 2048..2063
    thinA<<<BB/16, 256, 0, stream>>>(xh, xl, patTh, patTl, ha, w2t1, bs2, xh, xl);

    // h2 = relu(ri@Wr1 + br1), fused 3-term, split-bf16 out (K=2112 -> 33 BK64 iters)
    gemm_tile<true, true><<<1024, 256, 0, stream>>>(
        xh, xl, wr1h, wr1l, br1, ha, hb, 33, KEXT);

    // logits (3-term) + softmax + top4 + gates
    thinB<<<BB/16, 256, 0, stream>>>(ha, hb, wr2th, wr2tl, br2, cnt,
                                     out_gates, out_idx, out_probs);
}